// Round 5
// baseline (209.886 us; speedup 1.0000x reference)
//
#include <hip/hip_runtime.h>

#define HH 64
#define WW 64
#define CC 128
#define FF 256
#define NTAP 9
#define KD 1152   // NTAP*CC
#define XELEMS (8 * HH * WW * CC)         // 4194304
#define XCVT_BLOCKS (XELEMS / (256 * 8))  // 2048
#define WT_BLOCKS 144                     // 36864 threads, 8 k each

typedef __attribute__((ext_vector_type(8))) short bf16x8;
typedef __attribute__((ext_vector_type(4))) float floatx4;

__device__ inline unsigned short f2bf(float v) {
  union { float f; unsigned u; } c; c.f = v;
  unsigned r = (c.u + 0x7FFFu + ((c.u >> 16) & 1u)) >> 16;  // RNE
  return (unsigned short)r;
}
__device__ inline float bflo(unsigned u) {
  union { unsigned u; float f; } c; c.u = u << 16; return c.f;
}
__device__ inline float bfhi(unsigned u) {
  union { unsigned u; float f; } c; c.u = u & 0xFFFF0000u; return c.f;
}
// HW RNE pack: bf16(lo) | bf16(hi)<<16 — same rounding as f2bf for finite inputs.
__device__ inline unsigned cvt_pk_bf16(float lo, float hi) {
  unsigned r;
  asm("v_cvt_pk_bf16_f32 %0, %1, %2" : "=v"(r) : "v"(lo), "v"(hi));
  return r;
}

// Bilinear lerp of one 32-bit word (2 bf16 channels). Verified path (rounds 0-2,4).
__device__ inline unsigned lerp_word(unsigned u00, unsigned u10, unsigned u01, unsigned u11,
                                     float fy, float fx) {
  float v00 = bflo(u00), v10 = bflo(u10), v01 = bflo(u01), v11 = bflo(u11);
  float tx = v00 + (v10 - v00) * fy;
  float tb = v01 + (v11 - v01) * fy;
  float rlo = tx + (tb - tx) * fx;
  v00 = bfhi(u00); v10 = bfhi(u10); v01 = bfhi(u01); v11 = bfhi(u11);
  tx = v00 + (v10 - v00) * fy;
  tb = v01 + (v11 - v01) * fy;
  float rhi = tx + (tb - tx) * fx;
  return cvt_pk_bf16(rlo, rhi);
}

// Tap offsets packed 2 bits each (meshgrid-faithful order):
// c_iy = {0,0,1,2,2,1,0,2,1} -> 0x18690 ; c_ix = {0,1,1,2,0,2,1,0,2} -> 0x21894
#define IY_PACK 0x18690
#define IX_PACK 0x21894

struct ITap { int b00, b10, b01, b11; float fy, fx; };

__device__ inline ITap tap_from(float2 o2, int i, int p, int n) {
  float cy = (float)(i - 1 + ((IY_PACK >> (2 * n)) & 3)) + o2.x;
  float cx = (float)(p - 1 + ((IX_PACK >> (2 * n)) & 3)) + o2.y;
  cy = fminf(fmaxf(cy, 0.f), 63.f);
  cx = fminf(fmaxf(cx, 0.f), 63.f);
  const float fy0 = floorf(cy), fx0 = floorf(cx);
  const int y0 = (int)fy0, y1 = (int)ceilf(cy);
  const int x0 = (int)fx0, x1 = (int)ceilf(cx);
  ITap t;
  t.b00 = (y0 * WW + x0) * CC;
  t.b10 = (y1 * WW + x0) * CC;
  t.b01 = (y0 * WW + x1) * CC;
  t.b11 = (y1 * WW + x1) * CC;
  t.fy = cy - fy0;
  t.fx = cx - fx0;
  return t;
}

// ---- Prep: X fp32->bf16, and W [k][f] -> Wt [f][k] bf16 (verified rounds 0-2,4)
__global__ void prep_kernel(const float* __restrict__ X, const float* __restrict__ W,
                            unsigned short* __restrict__ Xb, unsigned short* __restrict__ Wt) {
  const int blk = blockIdx.x;
  if (blk < XCVT_BLOCKS) {                  // X convert, 8 elems/thread
    const int t = blk * 256 + threadIdx.x;
    const float4* src = (const float4*)(X + (size_t)t * 8);
    float4 a = src[0], b2 = src[1];
    bf16x8 o;
    o[0] = (short)f2bf(a.x);  o[1] = (short)f2bf(a.y);
    o[2] = (short)f2bf(a.z);  o[3] = (short)f2bf(a.w);
    o[4] = (short)f2bf(b2.x); o[5] = (short)f2bf(b2.y);
    o[6] = (short)f2bf(b2.z); o[7] = (short)f2bf(b2.w);
    *(bf16x8*)(Xb + (size_t)t * 8) = o;
  } else {                                  // W transpose: thread = (f, 8 k's)
    const int t = (blk - XCVT_BLOCKS) * 256 + threadIdx.x;  // 0..36863
    const int f = t & 255;
    const int k0 = (t >> 8) * 8;
    unsigned short o[8];
#pragma unroll
    for (int i2 = 0; i2 < 8; ++i2)
      o[i2] = f2bf(W[(size_t)(k0 + i2) * FF + f]);
    *(uint4*)(Wt + (size_t)f * KD + k0) = *(uint4*)o;
  }
}

// ---- Fused interp+GEMM: block = one image row = 64 M x 256 F, K = 1152.
// BK=128 (one full 3x3 tap per kt, 9 kt). 8 waves: kg = wave>>2 splits K in half,
// fg = wave&3 splits F; each wave computes 64M x 64F over its 64-k half (acc[4][4]);
// halves combined via LDS exchange, all 8 waves store 32 rows each (plain stores).
// Phase B: setup -> gathers issue -> B-DMA issue -> lerp (gather latency covered).
// LDS: smA 16KB + smB 64KB = 80KB -> 2 blocks/CU, 16 waves/CU.
__global__ __launch_bounds__(512, 4) void fused_kernel(
    const unsigned short* __restrict__ Xb, const float* __restrict__ Off,
    const unsigned short* __restrict__ Wt, const float* __restrict__ bias,
    float* __restrict__ Out)
{
  __shared__ unsigned short smA[64 * 128];     // 16 KB : 64 pos x 128 k (swizzled 16B chunks)
  __shared__ unsigned short smB[256 * 128];    // 64 KB : 256 F x 128 k (swizzled 16B chunks)

  const int blk = blockIdx.x;       // 0..511
  const int b   = blk & 7;          // batch == XCD -> Xb slice (1 MB) L2-resident
  const int i   = blk >> 3;         // image row y; positions x = 0..63
  const int m0  = (b * 64 + i) * 64;
  const int tid = threadIdx.x;
  const int wave = tid >> 6, lane = tid & 63;
  const int kg = wave >> 2;         // K-half of each tap
  const int fg = wave & 3;          // F quarter (64 F)
  const int arow = lane & 15, aq = lane >> 4;
  const int p  = tid >> 3;          // interp: position 0..63
  const int c0 = tid & 7;           // interp: chunks c0 and c0+8

  const unsigned short* xb = Xb + (size_t)b * (HH * WW * CC);
  const float* offp = Off + ((size_t)(b * HH + i) * WW + p) * (2 * NTAP);

  floatx4 acc[4][4];
#pragma unroll
  for (int mt = 0; mt < 4; ++mt)
#pragma unroll
    for (int ft = 0; ft < 4; ++ft)
      acc[mt][ft] = (floatx4){0.f, 0.f, 0.f, 0.f};

  // B staging: dest = wave-uniform base + lane*16B (linear); swizzle on global source.
#define STAGE_B(KT)                                                                  \
  {                                                                                  \
    _Pragma("unroll")                                                                \
    for (int pass = 0; pass < 8; ++pass) {                                           \
      const int row = pass * 32 + (tid >> 4);                                        \
      const int kc  = tid & 15;                                                      \
      const unsigned short* gp =                                                     \
          Wt + (size_t)row * KD + (KT) * 128 + ((kc ^ (row & 15)) << 3);             \
      unsigned short* l = (unsigned short*)&smB[row * 128 + kc * 8];                 \
      __builtin_amdgcn_global_load_lds(                                              \
          (const __attribute__((address_space(1))) unsigned int*)gp,                 \
          (__attribute__((address_space(3))) unsigned int*)l, 16, 0, 0);             \
    }                                                                                \
  }

  // ---- prologue: B tile 0 DMA + tap 0 interp
  STAGE_B(0)
  {
    ITap t = tap_from(*(const float2*)(offp), i, p, 0);
#pragma unroll
    for (int cc = 0; cc < 2; ++cc) {
      const int c  = c0 + cc * 8;
      const int ch = c * 8;
      uint4 q00 = *(const uint4*)(xb + t.b00 + ch);
      uint4 q10 = *(const uint4*)(xb + t.b10 + ch);
      uint4 q01 = *(const uint4*)(xb + t.b01 + ch);
      uint4 q11 = *(const uint4*)(xb + t.b11 + ch);
      unsigned w0 = lerp_word(q00.x, q10.x, q01.x, q11.x, t.fy, t.fx);
      unsigned w1 = lerp_word(q00.y, q10.y, q01.y, q11.y, t.fy, t.fx);
      unsigned w2 = lerp_word(q00.z, q10.z, q01.z, q11.z, t.fy, t.fx);
      unsigned w3 = lerp_word(q00.w, q10.w, q01.w, q11.w, t.fy, t.fx);
      *(uint4*)&smA[p * 128 + ((c ^ (p & 15)) << 3)] = make_uint4(w0, w1, w2, w3);
    }
  }
  __syncthreads();

  for (int kt = 0; kt < 9; ++kt) {
    // ---- phase A: prefetch next tap's offsets, then MFMA on this tap
    float2 off2;
    if (kt < 8) off2 = *(const float2*)(offp + 2 * (kt + 1));
#pragma unroll
    for (int ks = 0; ks < 2; ++ks) {
      bf16x8 afr[4], bfr[4];
      const int slot = (((kg * 8 + ks * 4 + aq) ^ arow) << 3);
#pragma unroll
      for (int mt = 0; mt < 4; ++mt)
        afr[mt] = *(const bf16x8*)&smA[(mt * 16 + arow) * 128 + slot];
#pragma unroll
      for (int ft = 0; ft < 4; ++ft)
        bfr[ft] = *(const bf16x8*)&smB[(fg * 64 + ft * 16 + arow) * 128 + slot];
#pragma unroll
      for (int mt = 0; mt < 4; ++mt)
#pragma unroll
        for (int ft = 0; ft < 4; ++ft)
          acc[mt][ft] = __builtin_amdgcn_mfma_f32_16x16x32_bf16(
              afr[mt], bfr[ft], acc[mt][ft], 0, 0, 0);
    }
    __syncthreads();   // all reads done -> buffers free for overwrite

    // ---- phase B: setup -> gathers issue -> B-DMA issue -> lerp -> smA write
    if (kt < 8) {
      ITap t = tap_from(off2, i, p, kt + 1);
      uint4 g[2][4];
#pragma unroll
      for (int cc = 0; cc < 2; ++cc) {      // all 8 gathers in flight first
        const int ch = (c0 + cc * 8) * 8;
        g[cc][0] = *(const uint4*)(xb + t.b00 + ch);
        g[cc][1] = *(const uint4*)(xb + t.b10 + ch);
        g[cc][2] = *(const uint4*)(xb + t.b01 + ch);
        g[cc][3] = *(const uint4*)(xb + t.b11 + ch);
      }
      STAGE_B(kt + 1)                       // DMA issues fly while gathers return
#pragma unroll
      for (int cc = 0; cc < 2; ++cc) {
        const int c = c0 + cc * 8;
        unsigned w0 = lerp_word(g[cc][0].x, g[cc][1].x, g[cc][2].x, g[cc][3].x, t.fy, t.fx);
        unsigned w1 = lerp_word(g[cc][0].y, g[cc][1].y, g[cc][2].y, g[cc][3].y, t.fy, t.fx);
        unsigned w2 = lerp_word(g[cc][0].z, g[cc][1].z, g[cc][2].z, g[cc][3].z, t.fy, t.fx);
        unsigned w3 = lerp_word(g[cc][0].w, g[cc][1].w, g[cc][2].w, g[cc][3].w, t.fy, t.fx);
        *(uint4*)&smA[p * 128 + ((c ^ (p & 15)) << 3)] = make_uint4(w0, w1, w2, w3);
      }
      __syncthreads();  // drains vmcnt (B-DMA) + lgkm (smA writes)
    }
  }
#undef STAGE_B

  // ---- epilogue: symmetric exchange; all 8 waves store 32 rows each (plain stores)
  // kg1 publishes mt{0,1}; kg0 publishes mt{2,3}; then kg0 stores rows 0..31,
  // kg1 stores rows 32..63. Slot s = mt*4+aq is globally unique per f.
  float* ex = (float*)smB;
  {
    const int mpub = kg ? 0 : 2;
#pragma unroll
    for (int mi = 0; mi < 2; ++mi) {
      const int mt = mpub + mi;
#pragma unroll
      for (int ft = 0; ft < 4; ++ft) {
        const int f = fg * 64 + ft * 16 + arow;
        const int s = mt * 4 + aq;
        *(floatx4*)&ex[f * 64 + ((s ^ arow) << 2)] = acc[mt][ft];
      }
    }
  }
  __syncthreads();
  {
    const int msto = kg ? 2 : 0;
    float bv[4];
#pragma unroll
    for (int ft = 0; ft < 4; ++ft)
      bv[ft] = bias[fg * 64 + ft * 16 + arow];
#pragma unroll
    for (int mi = 0; mi < 2; ++mi) {
      const int mt = msto + mi;
#pragma unroll
      for (int ft = 0; ft < 4; ++ft) {
        const int f = fg * 64 + ft * 16 + arow;
        const int s = mt * 4 + aq;
        floatx4 o = *(const floatx4*)&ex[f * 64 + ((s ^ arow) << 2)];
#pragma unroll
        for (int r = 0; r < 4; ++r) {
          const int m = m0 + mt * 16 + aq * 4 + r;
          Out[(size_t)m * FF + f] = acc[mt][ft][r] + o[r] + bv[ft];
        }
      }
    }
  }
}

extern "C" void kernel_launch(void* const* d_in, const int* in_sizes, int n_in,
                              void* d_out, int out_size, void* d_ws, size_t ws_size,
                              hipStream_t stream) {
  const float* X    = (const float*)d_in[0];
  const float* Off  = (const float*)d_in[1];
  const float* W    = (const float*)d_in[2];
  const float* bias = (const float*)d_in[3];
  float* Out = (float*)d_out;

  unsigned short* Wt = (unsigned short*)d_ws;                  // 294912 shorts
  unsigned short* Xb = Wt + (size_t)FF * KD;                   // 4194304 shorts

  prep_kernel<<<XCVT_BLOCKS + WT_BLOCKS, 256, 0, stream>>>(X, W, Xb, Wt);
  fused_kernel<<<512, 512, 0, stream>>>(Xb, Off, Wt, bias, Out);
}

// Round 6
// 112.358 us; speedup vs baseline: 1.8680x; 1.8680x over previous
//
#include <hip/hip_runtime.h>

#define HH 64
#define WW 64
#define CC 128
#define FF 256
#define NTAP 9
#define KD 1152   // NTAP*CC
#define XELEMS (8 * HH * WW * CC)         // 4194304
#define XCVT_BLOCKS (XELEMS / (256 * 8))  // 2048
#define WT_BLOCKS 144                     // 36864 threads, 8 k each

typedef __attribute__((ext_vector_type(8))) short bf16x8;
typedef __attribute__((ext_vector_type(4))) float floatx4;

__device__ inline unsigned short f2bf(float v) {
  union { float f; unsigned u; } c; c.f = v;
  unsigned r = (c.u + 0x7FFFu + ((c.u >> 16) & 1u)) >> 16;  // RNE
  return (unsigned short)r;
}
__device__ inline float bflo(unsigned u) {
  union { unsigned u; float f; } c; c.u = u << 16; return c.f;
}
__device__ inline float bfhi(unsigned u) {
  union { unsigned u; float f; } c; c.u = u & 0xFFFF0000u; return c.f;
}
// HW RNE pack: bf16(lo) | bf16(hi)<<16 — same rounding as f2bf for finite inputs.
__device__ inline unsigned cvt_pk_bf16(float lo, float hi) {
  unsigned r;
  asm("v_cvt_pk_bf16_f32 %0, %1, %2" : "=v"(r) : "v"(lo), "v"(hi));
  return r;
}

// Tap offsets packed 2 bits each (meshgrid-faithful order):
// c_iy = {0,0,1,2,2,1,0,2,1} -> 0x18690 ; c_ix = {0,1,1,2,0,2,1,0,2} -> 0x21894
#define IY_PACK 0x18690
#define IX_PACK 0x21894

// Weight-form bilinear: out = w00*v00 + w10*v10 + w01*v01 + w11*v11
// (expansion of the reference's sequential lerp; same within f32 rounding).
struct ITap { int b00, b10, b01, b11; float w00, w10, w01, w11; };

__device__ inline ITap tap_from(float2 o2, int i, int p, int n) {
  float cy = (float)(i - 1 + ((IY_PACK >> (2 * n)) & 3)) + o2.x;
  float cx = (float)(p - 1 + ((IX_PACK >> (2 * n)) & 3)) + o2.y;
  cy = fminf(fmaxf(cy, 0.f), 63.f);
  cx = fminf(fmaxf(cx, 0.f), 63.f);
  const float fy0 = floorf(cy), fx0 = floorf(cx);
  const int y0 = (int)fy0, y1 = (int)ceilf(cy);
  const int x0 = (int)fx0, x1 = (int)ceilf(cx);
  const float fy = cy - fy0, fx = cx - fx0;
  const float gy0 = 1.f - fy, gx0 = 1.f - fx;
  ITap t;
  t.b00 = (y0 * WW + x0) * CC;
  t.b10 = (y1 * WW + x0) * CC;
  t.b01 = (y0 * WW + x1) * CC;
  t.b11 = (y1 * WW + x1) * CC;
  t.w00 = gy0 * gx0;
  t.w10 = fy  * gx0;
  t.w01 = gy0 * fx;
  t.w11 = fy  * fx;
  return t;
}

__device__ inline unsigned lerp_word(unsigned u00, unsigned u10, unsigned u01, unsigned u11,
                                     const ITap& t) {
  float rlo = bflo(u00) * t.w00 + bflo(u10) * t.w10 + bflo(u01) * t.w01 + bflo(u11) * t.w11;
  float rhi = bfhi(u00) * t.w00 + bfhi(u10) * t.w10 + bfhi(u01) * t.w01 + bfhi(u11) * t.w11;
  return cvt_pk_bf16(rlo, rhi);
}

// ---- Prep: X fp32->bf16, and W [k][f] -> Wt [f][k] bf16 (verified rounds 0-2,4)
__global__ void prep_kernel(const float* __restrict__ X, const float* __restrict__ W,
                            unsigned short* __restrict__ Xb, unsigned short* __restrict__ Wt) {
  const int blk = blockIdx.x;
  if (blk < XCVT_BLOCKS) {                  // X convert, 8 elems/thread
    const int t = blk * 256 + threadIdx.x;
    const float4* src = (const float4*)(X + (size_t)t * 8);
    float4 a = src[0], b2 = src[1];
    bf16x8 o;
    o[0] = (short)f2bf(a.x);  o[1] = (short)f2bf(a.y);
    o[2] = (short)f2bf(a.z);  o[3] = (short)f2bf(a.w);
    o[4] = (short)f2bf(b2.x); o[5] = (short)f2bf(b2.y);
    o[6] = (short)f2bf(b2.z); o[7] = (short)f2bf(b2.w);
    *(bf16x8*)(Xb + (size_t)t * 8) = o;
  } else {                                  // W transpose: thread = (f, 8 k's)
    const int t = (blk - XCVT_BLOCKS) * 256 + threadIdx.x;  // 0..36863
    const int f = t & 255;
    const int k0 = (t >> 8) * 8;
    unsigned short o[8];
#pragma unroll
    for (int i2 = 0; i2 < 8; ++i2)
      o[i2] = f2bf(W[(size_t)(k0 + i2) * FF + f]);
    *(uint4*)(Wt + (size_t)f * KD + k0) = *(uint4*)o;
  }
}

// ---- Fused interp+GEMM: block = one image row = 64 M x 256 F, K = 1152, BK = 64.
// Round-2 schedule (gathers issued before register-only MFMA block = latency cover)
// + double-buffered LDS (ONE barrier per kt) + tap-setup-once-per-tap + weight lerp.
// 512 threads = 8 waves of 32M x 64F (acc[2][4]). LDS 2x(8+32) = 80 KB -> 2 blk/CU.
__global__ __launch_bounds__(512, 4) void fused_kernel(
    const unsigned short* __restrict__ Xb, const float* __restrict__ Off,
    const unsigned short* __restrict__ Wt, const float* __restrict__ bias,
    float* __restrict__ Out)
{
  __shared__ unsigned short smA[2][64 * 64];     // 2 x 8 KB
  __shared__ unsigned short smB[2][256 * 64];    // 2 x 32 KB

  const int blk = blockIdx.x;       // 0..511
  const int b   = blk & 7;          // batch == XCD -> Xb slice (1 MB) L2-resident
  const int i   = blk >> 3;         // image row y; positions x = 0..63
  const int m0  = (b * 64 + i) * 64;
  const int tid = threadIdx.x;
  const int wave = tid >> 6, lane = tid & 63;
  const int wm   = (wave & 1) * 32;     // wave: 32 M x 64 F
  const int wf   = (wave >> 1) * 64;
  const int arow = lane & 15, aq = lane >> 4;
  const int p  = tid >> 3;          // interp: position 0..63
  const int c0 = tid & 7;           // interp: one 8-channel chunk

  const unsigned short* xb = Xb + (size_t)b * (HH * WW * CC);
  const float* offp = Off + ((size_t)(b * HH + i) * WW + p) * (2 * NTAP);

  floatx4 acc[2][4];
#pragma unroll
  for (int mt = 0; mt < 2; ++mt)
#pragma unroll
    for (int ft = 0; ft < 4; ++ft)
      acc[mt][ft] = (floatx4){0.f, 0.f, 0.f, 0.f};

  // B staging: dest = wave-uniform base + lane*16B (linear in tid); swizzle on
  // the global source (inverse of read-side XOR). 4 passes x 512 thr x 16 B = 32 KB.
#define STAGE_B(KT, BUF)                                                             \
  {                                                                                  \
    _Pragma("unroll")                                                                \
    for (int pass = 0; pass < 4; ++pass) {                                           \
      const int row = pass * 64 + (tid >> 3);                                        \
      const int chp = c0 ^ (row & 7);                                                \
      const unsigned short* gp = Wt + (size_t)row * KD + (KT) * 64 + chp * 8;        \
      unsigned short* l = (unsigned short*)&smB[BUF][row * 64 + c0 * 8];             \
      __builtin_amdgcn_global_load_lds(                                              \
          (const __attribute__((address_space(1))) unsigned int*)gp,                 \
          (__attribute__((address_space(3))) unsigned int*)l, 16, 0, 0);             \
    }                                                                                \
  }

  // ---- prologue: tap 0 setup, interp half 0 -> smA[0], B tile 0 -> smB[0]
  ITap t = tap_from(*(const float2*)offp, i, p, 0);
  STAGE_B(0, 0)
  {
    const int ch = c0 * 8;   // tap 0, half 0
    uint4 q00 = *(const uint4*)(xb + t.b00 + ch);
    uint4 q10 = *(const uint4*)(xb + t.b10 + ch);
    uint4 q01 = *(const uint4*)(xb + t.b01 + ch);
    uint4 q11 = *(const uint4*)(xb + t.b11 + ch);
    unsigned w0 = lerp_word(q00.x, q10.x, q01.x, q11.x, t);
    unsigned w1 = lerp_word(q00.y, q10.y, q01.y, q11.y, t);
    unsigned w2 = lerp_word(q00.z, q10.z, q01.z, q11.z, t);
    unsigned w3 = lerp_word(q00.w, q10.w, q01.w, q11.w, t);
    *(uint4*)&smA[0][p * 64 + ((c0 ^ (p & 7)) << 3)] = make_uint4(w0, w1, w2, w3);
  }
  __syncthreads();

  int cur = 0;
  for (int kt = 0; kt < 18; ++kt) {
    // ---- pull this tile's fragments into registers (ds reads, fast)
    bf16x8 afr[2][2], bfr[2][4];
#pragma unroll
    for (int ks = 0; ks < 2; ++ks) {
      const int slot = (((ks * 4 + aq) ^ (arow & 7)) << 3);
#pragma unroll
      for (int mt = 0; mt < 2; ++mt)
        afr[ks][mt] = *(const bf16x8*)&smA[cur][(wm + mt * 16 + arow) * 64 + slot];
#pragma unroll
      for (int ft = 0; ft < 4; ++ft)
        bfr[ks][ft] = *(const bf16x8*)&smB[cur][(wf + ft * 16 + arow) * 64 + slot];
    }

    // ---- issue next tile's work into buf cur^1 (covered by the MFMAs below)
    const int nk = kt + 1;
    uint4 g0, g1, g2, g3;
    if (nk < 18) {
      if ((nk & 1) == 0)   // entering a new tap: fresh setup (once per tap)
        t = tap_from(*(const float2*)(offp + 2 * (nk >> 1)), i, p, nk >> 1);
      const int ch = ((nk & 1) * 8 + c0) * 8;
      g0 = *(const uint4*)(xb + t.b00 + ch);
      g1 = *(const uint4*)(xb + t.b10 + ch);
      g2 = *(const uint4*)(xb + t.b01 + ch);
      g3 = *(const uint4*)(xb + t.b11 + ch);
      STAGE_B(nk, cur ^ 1)
    }

    // ---- MFMA on registers (covers gather + DMA latency)
#pragma unroll
    for (int ks = 0; ks < 2; ++ks)
#pragma unroll
      for (int mt = 0; mt < 2; ++mt)
#pragma unroll
        for (int ft = 0; ft < 4; ++ft)
          acc[mt][ft] = __builtin_amdgcn_mfma_f32_16x16x32_bf16(
              afr[ks][mt], bfr[ks][ft], acc[mt][ft], 0, 0, 0);

    // ---- finish interp of next tile
    if (nk < 18) {
      unsigned w0 = lerp_word(g0.x, g1.x, g2.x, g3.x, t);
      unsigned w1 = lerp_word(g0.y, g1.y, g2.y, g3.y, t);
      unsigned w2 = lerp_word(g0.z, g1.z, g2.z, g3.z, t);
      unsigned w3 = lerp_word(g0.w, g1.w, g2.w, g3.w, t);
      *(uint4*)&smA[cur ^ 1][p * 64 + ((c0 ^ (p & 7)) << 3)] = make_uint4(w0, w1, w2, w3);
    }
    __syncthreads();   // drains vmcnt (B-DMA) + lgkm (smA writes); flips buffer
    cur ^= 1;
  }
#undef STAGE_B

  // ---- epilogue (round-2 verified plain-store pattern)
  float bv[4];
#pragma unroll
  for (int ft = 0; ft < 4; ++ft)
    bv[ft] = bias[wf + ft * 16 + arow];
#pragma unroll
  for (int mt = 0; mt < 2; ++mt) {
#pragma unroll
    for (int ft = 0; ft < 4; ++ft) {
      const int f = wf + ft * 16 + arow;
#pragma unroll
      for (int r = 0; r < 4; ++r) {
        const int m = m0 + wm + mt * 16 + aq * 4 + r;
        Out[(size_t)m * FF + f] = acc[mt][ft][r] + bv[ft];
      }
    }
  }
}

extern "C" void kernel_launch(void* const* d_in, const int* in_sizes, int n_in,
                              void* d_out, int out_size, void* d_ws, size_t ws_size,
                              hipStream_t stream) {
  const float* X    = (const float*)d_in[0];
  const float* Off  = (const float*)d_in[1];
  const float* W    = (const float*)d_in[2];
  const float* bias = (const float*)d_in[3];
  float* Out = (float*)d_out;

  unsigned short* Wt = (unsigned short*)d_ws;                  // 294912 shorts
  unsigned short* Xb = Wt + (size_t)FF * KD;                   // 4194304 shorts

  prep_kernel<<<XCVT_BLOCKS + WT_BLOCKS, 256, 0, stream>>>(X, W, Xb, Wt);
  fused_kernel<<<512, 512, 0, stream>>>(Xb, Off, Wt, bias, Out);
}

// Round 7
// 110.069 us; speedup vs baseline: 1.9069x; 1.0208x over previous
//
#include <hip/hip_runtime.h>

#define HH 64
#define WW 64
#define CC 128
#define FF 256
#define NTAP 9
#define KD 1152   // NTAP*CC
#define XELEMS (8 * HH * WW * CC)         // 4194304
#define XCVT_BLOCKS (XELEMS / (256 * 8))  // 2048
#define WT_BLOCKS 144                     // 36864 threads, 8 k each

typedef __attribute__((ext_vector_type(8))) short bf16x8;
typedef __attribute__((ext_vector_type(4))) float floatx4;

__device__ inline unsigned short f2bf(float v) {
  union { float f; unsigned u; } c; c.f = v;
  unsigned r = (c.u + 0x7FFFu + ((c.u >> 16) & 1u)) >> 16;  // RNE
  return (unsigned short)r;
}
__device__ inline float bflo(unsigned u) {
  union { unsigned u; float f; } c; c.u = u << 16; return c.f;
}
__device__ inline float bfhi(unsigned u) {
  union { unsigned u; float f; } c; c.u = u & 0xFFFF0000u; return c.f;
}
// HW RNE pack: bf16(lo) | bf16(hi)<<16 — same rounding as f2bf for finite inputs.
__device__ inline unsigned cvt_pk_bf16(float lo, float hi) {
  unsigned r;
  asm("v_cvt_pk_bf16_f32 %0, %1, %2" : "=v"(r) : "v"(lo), "v"(hi));
  return r;
}

// Weight-form bilinear (verified round 6): out = w00*v00 + w10*v10 + w01*v01 + w11*v11
__device__ inline unsigned lerp_word(unsigned u00, unsigned u10, unsigned u01, unsigned u11,
                                     float w00, float w10, float w01, float w11) {
  float rlo = bflo(u00) * w00 + bflo(u10) * w10 + bflo(u01) * w01 + bflo(u11) * w11;
  float rhi = bfhi(u00) * w00 + bfhi(u10) * w10 + bfhi(u01) * w01 + bfhi(u11) * w11;
  return cvt_pk_bf16(rlo, rhi);
}

// Tap offsets packed 2 bits each (meshgrid-faithful order):
// c_iy = {0,0,1,2,2,1,0,2,1} -> 0x18690 ; c_ix = {0,1,1,2,0,2,1,0,2} -> 0x21894
#define IY_PACK 0x18690
#define IX_PACK 0x21894

struct ITap { int b00, b10, b01, b11; float fy, fx; };

__device__ inline ITap tap_from(float2 o2, int yy, int xx, int n) {
  float cy = (float)(yy - 1 + ((IY_PACK >> (2 * n)) & 3)) + o2.x;
  float cx = (float)(xx - 1 + ((IX_PACK >> (2 * n)) & 3)) + o2.y;
  cy = fminf(fmaxf(cy, 0.f), 63.f);
  cx = fminf(fmaxf(cx, 0.f), 63.f);
  const float fy0 = floorf(cy), fx0 = floorf(cx);
  const int y0 = (int)fy0, y1 = (int)ceilf(cy);
  const int x0 = (int)fx0, x1 = (int)ceilf(cx);
  ITap t;
  t.b00 = (y0 * WW + x0) * CC;
  t.b10 = (y1 * WW + x0) * CC;
  t.b01 = (y0 * WW + x1) * CC;
  t.b11 = (y1 * WW + x1) * CC;
  t.fy = cy - fy0;
  t.fx = cx - fx0;
  return t;
}

// ---- Prep: X fp32->bf16 (unchanged); W -> Wtf in MFMA-FRAGMENT order:
// addr(f,kc) = ((kt*2+ks)*16 + fg*4 + ft)*512 + aq*128 + arow*8   (shorts)
// where kc = kt*8+ks*4+aq (8-elem k-chunk), f = fg*64+ft*16+arow.
// A B-fragment read is then base + lane*16B — perfectly coalesced from L2.
__global__ void prep_kernel(const float* __restrict__ X, const float* __restrict__ W,
                            unsigned short* __restrict__ Xb, unsigned short* __restrict__ Wtf) {
  const int blk = blockIdx.x;
  if (blk < XCVT_BLOCKS) {                  // X convert, 8 elems/thread
    const int t = blk * 256 + threadIdx.x;
    const float4* src = (const float4*)(X + (size_t)t * 8);
    float4 a = src[0], b2 = src[1];
    bf16x8 o;
    o[0] = (short)f2bf(a.x);  o[1] = (short)f2bf(a.y);
    o[2] = (short)f2bf(a.z);  o[3] = (short)f2bf(a.w);
    o[4] = (short)f2bf(b2.x); o[5] = (short)f2bf(b2.y);
    o[6] = (short)f2bf(b2.z); o[7] = (short)f2bf(b2.w);
    *(bf16x8*)(Xb + (size_t)t * 8) = o;
  } else {                                  // W repack: thread = (f, one 8-k chunk)
    const int t = (blk - XCVT_BLOCKS) * 256 + threadIdx.x;  // 0..36863
    const int f  = t & 255;
    const int kc = t >> 8;                  // 0..143
    unsigned short o[8];
#pragma unroll
    for (int j = 0; j < 8; ++j)
      o[j] = f2bf(W[(size_t)(kc * 8 + j) * FF + f]);  // lanes: consecutive f -> coalesced read
    const int kt = kc >> 3, ks = (kc >> 2) & 1, aq = kc & 3;
    const int fg = f >> 6, ft = (f >> 4) & 3, arow = f & 15;
    const size_t addr = (size_t)((kt * 2 + ks) * 16 + fg * 4 + ft) * 512 + aq * 128 + arow * 8;
    *(uint4*)(Wtf + addr) = *(uint4*)o;
  }
}

// ---- Fused interp+GEMM: block = 32 M x 256 F, K = 1152, BK = 64 (half-tap / kt).
// NO B-staging: B fragments load straight from L2-resident Wtf (fragment-ordered).
// LDS = smA[2] only (8 KB) -> grid 1024, 4 independent blocks/CU, 16 waves/CU.
// Pipeline: gathers for tile kt+2 issued at kt, lerped at kt+1 (cross-barrier cover);
// B-ks0 issued at top of kt, consumed after afr+lerp+gather-issue (~250 cyc cover).
// One barrier/kt protecting only the 4 KB smA write.
__global__ __launch_bounds__(256, 4) void fused_kernel(
    const unsigned short* __restrict__ Xb, const float* __restrict__ Off,
    const unsigned short* __restrict__ Wtf, const float* __restrict__ bias,
    float* __restrict__ Out)
{
  __shared__ unsigned short smA[2][32 * 64];   // 2 x 4 KB, XOR-swizzled 16B chunks

  const int blk = blockIdx.x;        // 0..1023
  const int b   = blk & 7;           // batch == XCD -> Xb slice (1 MB) + Wtf L2-resident
  const int i   = blk >> 3;          // 0..127 : (row y = i>>1, x-half = i&1)
  const int y   = i >> 1;
  const int m0  = b * 4096 + i * 32;
  const int tid = threadIdx.x;
  const int wave = tid >> 6, lane = tid & 63;   // wave = F-quarter fg
  const int arow = lane & 15, aq = lane >> 4;
  const int p   = tid >> 3;          // 0..31 : position within block
  const int c0  = tid & 7;           // one 8-channel chunk
  const int px  = (i & 1) * 32 + p;  // x position 0..63

  const unsigned short* xb   = Xb + (size_t)b * (HH * WW * CC);
  const float* offp          = Off + ((size_t)(b * HH + y) * WW + px) * (2 * NTAP);
  const unsigned short* wbase = Wtf + (size_t)wave * 2048 + (size_t)lane * 8;

  floatx4 acc[2][4];
#pragma unroll
  for (int mt = 0; mt < 2; ++mt)
#pragma unroll
    for (int ft = 0; ft < 4; ++ft)
      acc[mt][ft] = (floatx4){0.f, 0.f, 0.f, 0.f};

  const int sa_off = p * 64 + ((c0 ^ (p & 7)) << 3);

  // ---- prologue: tap 0; lerp tile 0 -> smA[0]; gather tile 1 into regs
  ITap tL = tap_from(*(const float2*)offp, y, px, 0);
  uint4 g0, g1, g2, g3;
  {
    const int ch = c0 * 8;   // tile 0 = tap 0, half 0
    uint4 q00 = *(const uint4*)(xb + tL.b00 + ch);
    uint4 q10 = *(const uint4*)(xb + tL.b10 + ch);
    uint4 q01 = *(const uint4*)(xb + tL.b01 + ch);
    uint4 q11 = *(const uint4*)(xb + tL.b11 + ch);
    const float gy = 1.f - tL.fy, gx = 1.f - tL.fx;
    const float w00 = gy * gx, w10 = tL.fy * gx, w01 = gy * tL.fx, w11 = tL.fy * tL.fx;
    uint4 o;
    o.x = lerp_word(q00.x, q10.x, q01.x, q11.x, w00, w10, w01, w11);
    o.y = lerp_word(q00.y, q10.y, q01.y, q11.y, w00, w10, w01, w11);
    o.z = lerp_word(q00.z, q10.z, q01.z, q11.z, w00, w10, w01, w11);
    o.w = lerp_word(q00.w, q10.w, q01.w, q11.w, w00, w10, w01, w11);
    *(uint4*)&smA[0][sa_off] = o;
    const int ch1 = (8 + c0) * 8;  // tile 1 = tap 0, half 1
    g0 = *(const uint4*)(xb + tL.b00 + ch1);
    g1 = *(const uint4*)(xb + tL.b10 + ch1);
    g2 = *(const uint4*)(xb + tL.b01 + ch1);
    g3 = *(const uint4*)(xb + tL.b11 + ch1);
  }
  ITap tG = tL;
  __syncthreads();

  int cur = 0;
  for (int kt = 0; kt < 18; ++kt) {
    const unsigned short* wk = wbase + (size_t)kt * 16384;  // (kt*2)*16*512 shorts

    // ---- B ks=0 fragment loads (straight from L2, coalesced)
    bf16x8 b0[4], b1[4];
#pragma unroll
    for (int ft = 0; ft < 4; ++ft)
      b0[ft] = *(const bf16x8*)(wk + ft * 512);

    // ---- A fragments from smA[cur]
    bf16x8 afr[2][2];
#pragma unroll
    for (int ks = 0; ks < 2; ++ks) {
      const int slot = (((ks * 4 + aq) ^ (arow & 7)) << 3);
#pragma unroll
      for (int mt = 0; mt < 2; ++mt)
        afr[ks][mt] = *(const bf16x8*)&smA[cur][(mt * 16 + arow) * 64 + slot];
    }

    // ---- lerp the gathers from last iteration -> tile kt+1 into smA[cur^1]
    if (kt <= 16) {
      const float gy = 1.f - tL.fy, gx = 1.f - tL.fx;
      const float w00 = gy * gx, w10 = tL.fy * gx, w01 = gy * tL.fx, w11 = tL.fy * tL.fx;
      uint4 o;
      o.x = lerp_word(g0.x, g1.x, g2.x, g3.x, w00, w10, w01, w11);
      o.y = lerp_word(g0.y, g1.y, g2.y, g3.y, w00, w10, w01, w11);
      o.z = lerp_word(g0.z, g1.z, g2.z, g3.z, w00, w10, w01, w11);
      o.w = lerp_word(g0.w, g1.w, g2.w, g3.w, w00, w10, w01, w11);
      *(uint4*)&smA[cur ^ 1][sa_off] = o;
    }

    // ---- B ks=1 fragment loads
#pragma unroll
    for (int ft = 0; ft < 4; ++ft)
      b1[ft] = *(const bf16x8*)(wk + 8192 + ft * 512);

    // ---- issue gathers for tile kt+2 (consumed next iteration, cross-barrier)
    if (kt <= 15) {
      if ((kt & 1) == 0)
        tG = tap_from(*(const float2*)(offp + 2 * ((kt + 2) >> 1)), y, px, (kt + 2) >> 1);
      const int ch = ((kt & 1) * 8 + c0) * 8;   // half of tile kt+2 = (kt+2)&1 = kt&1
      g0 = *(const uint4*)(xb + tG.b00 + ch);
      g1 = *(const uint4*)(xb + tG.b10 + ch);
      g2 = *(const uint4*)(xb + tG.b01 + ch);
      g3 = *(const uint4*)(xb + tG.b11 + ch);
    }

    // ---- MFMA (b0 covered by afr+lerp; b1 covered by gathers + ks0 block)
#pragma unroll
    for (int mt = 0; mt < 2; ++mt)
#pragma unroll
      for (int ft = 0; ft < 4; ++ft)
        acc[mt][ft] = __builtin_amdgcn_mfma_f32_16x16x32_bf16(
            afr[0][mt], b0[ft], acc[mt][ft], 0, 0, 0);
#pragma unroll
    for (int mt = 0; mt < 2; ++mt)
#pragma unroll
      for (int ft = 0; ft < 4; ++ft)
        acc[mt][ft] = __builtin_amdgcn_mfma_f32_16x16x32_bf16(
            afr[1][mt], b1[ft], acc[mt][ft], 0, 0, 0);

    __syncthreads();   // drains lgkm (smA writes); gathers have MFMA-phase cover
    cur ^= 1;
    tL = tG;
  }

  // ---- epilogue: plain stores (verified clean-write pattern)
  float bv[4];
#pragma unroll
  for (int ft = 0; ft < 4; ++ft)
    bv[ft] = bias[wave * 64 + ft * 16 + arow];
#pragma unroll
  for (int mt = 0; mt < 2; ++mt) {
#pragma unroll
    for (int ft = 0; ft < 4; ++ft) {
      const int f = wave * 64 + ft * 16 + arow;
#pragma unroll
      for (int r = 0; r < 4; ++r) {
        const int m = m0 + mt * 16 + aq * 4 + r;
        Out[(size_t)m * FF + f] = acc[mt][ft][r] + bv[ft];
      }
    }
  }
}

extern "C" void kernel_launch(void* const* d_in, const int* in_sizes, int n_in,
                              void* d_out, int out_size, void* d_ws, size_t ws_size,
                              hipStream_t stream) {
  const float* X    = (const float*)d_in[0];
  const float* Off  = (const float*)d_in[1];
  const float* W    = (const float*)d_in[2];
  const float* bias = (const float*)d_in[3];
  float* Out = (float*)d_out;

  unsigned short* Wtf = (unsigned short*)d_ws;                 // 294912 shorts
  unsigned short* Xb  = Wtf + (size_t)FF * KD;                 // 4194304 shorts

  prep_kernel<<<XCVT_BLOCKS + WT_BLOCKS, 256, 0, stream>>>(X, W, Xb, Wtf);
  fused_kernel<<<1024, 256, 0, stream>>>(Xb, Off, Wtf, bias, Out);
}